// Round 1
// baseline (842.709 us; speedup 1.0000x reference)
//
#include <hip/hip_runtime.h>
#include <math.h>

#define B_  2
#define H_  64
#define W_  64
#define HW  4096
#define DM  96
#define DI  192
#define NS  4
#define RK  6
#define KD  2
#define LL  8192   // 2*HW

__device__ __forceinline__ float sigmoidf_(float x){ return 1.f/(1.f+__expf(-x)); }

// ---------------- K1: input projections -> channel-major [B,DI,HW] ----------------
__global__ __launch_bounds__(256) void k_inproj(
    const float* __restrict__ xrgb, const float* __restrict__ xe,
    const float* __restrict__ wr,   const float* __restrict__ we,
    float* __restrict__ xrt, float* __restrict__ xet)
{
  const int mod = blockIdx.z;
  const float* x  = mod ? xe  : xrgb;
  const float* Wp = mod ? we  : wr;
  float* out      = mod ? xet : xrt;
  const int b   = blockIdx.y;
  const int hw0 = blockIdx.x * 64;
  __shared__ float ls[64][97];
  const int tid = threadIdx.x;
  const float* src = x + ((size_t)b*HW + hw0)*DM;
  for (int t = tid; t < 64*DM; t += 256) ls[t/DM][t%DM] = src[t];
  __syncthreads();
  const int hw_i = tid & 63, wslot = tid >> 6;   // wslot picks 48 output channels
  float acc[48];
  #pragma unroll
  for (int q=0;q<48;q++) acc[q]=0.f;
  const float* wbase = Wp + (size_t)(wslot*48)*DM;
  for (int m=0;m<DM;m++){
    float xv = ls[hw_i][m];
    #pragma unroll
    for (int q=0;q<48;q++) acc[q] += wbase[q*DM + m] * xv;
  }
  #pragma unroll
  for (int q=0;q<48;q++){
    int dd = wslot*48 + q;
    out[((size_t)b*DI + dd)*HW + hw0 + hw_i] = acc[q];
  }
}

// ---------------- K2: depthwise 3x3 conv + SiLU -> seq[B,DI,2HW] ----------------
__global__ __launch_bounds__(256) void k_conv(
    const float* __restrict__ xrt, const float* __restrict__ xet,
    const float* __restrict__ cwr, const float* __restrict__ cbr,
    const float* __restrict__ cwe, const float* __restrict__ cbe,
    float* __restrict__ seq)
{
  const int z = blockIdx.z; const int b = z >> 1, mod = z & 1;
  const int d = blockIdx.y;
  const float* in = (mod? xet:xrt) + ((size_t)b*DI + d)*HW;
  const float* wp = (mod? cwe:cwr) + d*9;
  const float  bias = (mod? cbe:cbr)[d];
  const int hw = blockIdx.x*256 + threadIdx.x;
  const int y = hw >> 6, x = hw & 63;
  float w[9];
  #pragma unroll
  for (int i=0;i<9;i++) w[i]=wp[i];
  float acc = bias;
  #pragma unroll
  for (int dy=-1;dy<=1;dy++){
    int yy = y+dy;
    if (yy<0||yy>=H_) continue;
    #pragma unroll
    for (int dx=-1;dx<=1;dx++){
      int xx = x+dx;
      if (xx<0||xx>=W_) continue;
      acc += in[yy*W_+xx]*w[(dy+1)*3 + dx+1];
    }
  }
  float v = acc * sigmoidf_(acc);
  seq[((size_t)b*DI + d)*LL + mod*HW + hw] = v;
}

// ---------------- K3a: per-channel spatial mean of pre-conv features ----------------
__global__ __launch_bounds__(256) void k_mean(
    const float* __restrict__ xrt, const float* __restrict__ xet, float* __restrict__ sr)
{
  const int mod = blockIdx.z, b = blockIdx.y, d = blockIdx.x;
  const float* in = (mod? xet:xrt) + ((size_t)b*DI + d)*HW;
  float s = 0.f;
  for (int i=threadIdx.x; i<HW; i+=256) s += in[i];
  #pragma unroll
  for (int off=32; off; off>>=1) s += __shfl_down(s, off, 64);
  __shared__ float ps[4];
  if ((threadIdx.x & 63)==0) ps[threadIdx.x>>6] = s;
  __syncthreads();
  if (threadIdx.x==0)
    sr[((size_t)mod*B_ + b)*DI + d] = (ps[0]+ps[1]+ps[2]+ps[3]) * (1.f/HW);
}

// ---------------- K3b: squeeze-excitation MLP ----------------
__global__ void k_se(const float* __restrict__ sr,
                     const float* __restrict__ f11, const float* __restrict__ f12,
                     const float* __restrict__ f21, const float* __restrict__ f22,
                     float* __restrict__ ex)
{
  const int b = blockIdx.x, mod = blockIdx.y;
  const float* f1 = mod? f21:f11;
  const float* f2 = mod? f22:f12;
  __shared__ float s[DI];
  __shared__ float hid[12];
  const int t = threadIdx.x;
  s[t] = sr[((size_t)mod*B_ + b)*DI + t];
  __syncthreads();
  if (t < 12){
    float a=0.f;
    for (int dd=0; dd<DI; dd++) a += f1[t*DI+dd]*s[dd];
    hid[t] = a * sigmoidf_(a);
  }
  __syncthreads();
  float a=0.f;
  #pragma unroll
  for (int h=0; h<12; h++) a += f2[t*12+h]*hid[h];
  ex[((size_t)mod*B_ + b)*DI + t] = sigmoidf_(a);
}

// ---------------- K4: x_proj of seq for both k (natural j order) ----------------
__global__ __launch_bounds__(256) void k_pdbl(
    const float* __restrict__ seq, const float* __restrict__ xpw, float* __restrict__ pdbl)
{
  const int c = blockIdx.y;
  const int z = blockIdx.z; const int b = z>>1, k = z&1;
  const int j = blockIdx.x*256 + threadIdx.x;
  const float* wrow = xpw + (size_t)(k*14 + c)*DI;
  const float* sq   = seq + (size_t)b*DI*LL + j;
  float acc=0.f;
  for (int d=0; d<DI; d++) acc += wrow[d]*sq[(size_t)d*LL];
  pdbl[(((size_t)b*KD + k)*14 + c)*LL + j] = acc;
}

// ---------------- K5: chunked selective scan ----------------
#define CHUNK 32
#define NCH   256
__global__ __launch_bounds__(256) void k_scan(
    const float* __restrict__ seq,  const float* __restrict__ pdbl,
    const float* __restrict__ dtw,  const float* __restrict__ dtb,
    const float* __restrict__ Alogs,const float* __restrict__ Dsp,
    float* __restrict__ y0, float* __restrict__ y1)
{
  const int gid = blockIdx.x;
  const int d = gid % DI;
  const int k = (gid / DI) % KD;
  const int b = gid / (DI*KD);
  const int c = threadIdx.x;
  const int kd = k*DI + d;
  float A[NS];
  #pragma unroll
  for (int n=0;n<NS;n++) A[n] = -__expf(Alogs[kd*NS+n]);
  float dwv[RK];
  #pragma unroll
  for (int r=0;r<RK;r++) dwv[r] = dtw[kd*RK+r];
  const float bias = dtb[kd];
  const float Dv   = Dsp[kd];
  const float* sq = seq + ((size_t)b*DI + d)*LL;
  const float* pb = pdbl + ((size_t)(b*KD + k))*14*LL;

  __shared__ float sP[NCH][NS+1];
  __shared__ float sH[NCH][NS+1];

  // Phase A: local chunk scan with zero init
  float hP[NS], hh[NS];
  #pragma unroll
  for (int n=0;n<NS;n++){ hP[n]=1.f; hh[n]=0.f; }
  const int l0 = c*CHUNK;
  for (int i=0;i<CHUNK;i++){
    int l = l0 + i;
    int j = k ? (LL-1-l) : l;
    float x = sq[j];
    float acc = bias;
    #pragma unroll
    for (int r=0;r<RK;r++) acc += dwv[r]*pb[r*LL + j];
    float delta = (acc > 20.f) ? acc : log1pf(__expf(acc));
    float du = delta*x;
    #pragma unroll
    for (int n=0;n<NS;n++){
      float dA = __expf(delta*A[n]);
      float Bv = pb[(RK+n)*LL + j];
      hh[n] = dA*hh[n] + du*Bv;
      hP[n] *= dA;
    }
  }
  #pragma unroll
  for (int n=0;n<NS;n++){ sP[c][n]=hP[n]; sH[c][n]=hh[n]; }
  __syncthreads();

  // Hillis-Steele inclusive scan over chunk carries: combine(old,new)=(a_o*a_n, a_n*h_o+h_n)
  float aC[NS], hC[NS];
  #pragma unroll
  for (int n=0;n<NS;n++){ aC[n]=hP[n]; hC[n]=hh[n]; }
  for (int s=1; s<NCH; s<<=1){
    float aO[NS], hO[NS];
    if (c >= s){
      #pragma unroll
      for (int n=0;n<NS;n++){ aO[n]=sP[c-s][n]; hO[n]=sH[c-s][n]; }
    }
    __syncthreads();
    if (c >= s){
      #pragma unroll
      for (int n=0;n<NS;n++){
        hC[n] = aC[n]*hO[n] + hC[n];
        aC[n] = aC[n]*aO[n];
        sP[c][n]=aC[n]; sH[c][n]=hC[n];
      }
    }
    __syncthreads();
  }
  float hi[NS];
  #pragma unroll
  for (int n=0;n<NS;n++) hi[n] = (c==0)? 0.f : sH[c-1][n];

  // Phase B: re-scan with correct init, emit y
  float* yo = (k ? y1 : y0) + ((size_t)b*DI + d)*LL;
  float h[NS];
  #pragma unroll
  for (int n=0;n<NS;n++) h[n]=hi[n];
  for (int i=0;i<CHUNK;i++){
    int l = l0 + i;
    int j = k ? (LL-1-l) : l;
    float x = sq[j];
    float acc = bias;
    #pragma unroll
    for (int r=0;r<RK;r++) acc += dwv[r]*pb[r*LL + j];
    float delta = (acc > 20.f) ? acc : log1pf(__expf(acc));
    float du = delta*x;
    float y = Dv*x;
    #pragma unroll
    for (int n=0;n<NS;n++){
      float dA = __expf(delta*A[n]);
      float Bv = pb[(RK+n)*LL + j];
      float Cv = pb[(RK+NS+n)*LL + j];
      h[n] = dA*h[n] + du*Bv;
      y += Cv*h[n];
    }
    yo[j] = y;
  }
}

// ---------------- K6: merge + LayerNorm + SE scale -> yln[B,L,DI] ----------------
__global__ __launch_bounds__(256) void k_ln(
    const float* __restrict__ y0, const float* __restrict__ y1,
    const float* __restrict__ ln1g, const float* __restrict__ ln1b,
    const float* __restrict__ ln2g, const float* __restrict__ ln2b,
    const float* __restrict__ ex, float* __restrict__ yln)
{
  const int b  = blockIdx.y;
  const int j0 = blockIdx.x*64;
  __shared__ float v[DI][65];
  __shared__ float ps1[4][64], ps2[4][64];
  __shared__ float mu[64], rs[64];
  const int tid = threadIdx.x;
  const int jl = tid & 63, ds = tid >> 6;
  const float* p0 = y0 + (size_t)b*DI*LL + j0;
  const float* p1 = y1 + (size_t)b*DI*LL + j0;
  for (int it=0; it<48; it++){
    int d = ds*48 + it;
    v[d][jl] = p0[(size_t)d*LL + jl] + p1[(size_t)d*LL + jl];
  }
  __syncthreads();
  float s1=0.f, s2=0.f;
  for (int it=0; it<48; it++){
    float x = v[ds*48+it][jl];
    s1 += x; s2 += x*x;
  }
  ps1[ds][jl]=s1; ps2[ds][jl]=s2;
  __syncthreads();
  if (tid < 64){
    float t1 = ps1[0][tid]+ps1[1][tid]+ps1[2][tid]+ps1[3][tid];
    float t2 = ps2[0][tid]+ps2[1][tid]+ps2[2][tid]+ps2[3][tid];
    float m  = t1*(1.f/DI);
    float var= t2*(1.f/DI) - m*m;
    mu[tid]=m; rs[tid]=rsqrtf(var + 1e-5f);
  }
  __syncthreads();
  const int mod = (j0 >= HW) ? 1 : 0;
  const float* g  = mod? ln2g:ln1g;
  const float* bb = mod? ln2b:ln1b;
  const float* exm = ex + ((size_t)mod*B_ + b)*DI;
  for (int it=0; it<48; it++){
    int idx = it*256 + tid;
    int j = idx / DI;
    int d = idx - j*DI;
    float x = v[d][j];
    float o = (x - mu[j])*rs[j]*g[d] + bb[d];
    o *= exm[d];
    yln[((size_t)b*LL + j0 + j)*DI + d] = o;
  }
}

// ---------------- K7: output projection ----------------
__global__ __launch_bounds__(256) void k_out(
    const float* __restrict__ yln, const float* __restrict__ Wo, float* __restrict__ out)
{
  const int b   = blockIdx.y;
  const int hw0 = blockIdx.x*64;
  __shared__ float ls[64][193];
  const int tid = threadIdx.x;
  const int hwi = tid & 63, ws = tid >> 6;
  float acc[24];
  #pragma unroll
  for (int q=0;q<24;q++) acc[q]=0.f;

  // rgb half: rows j = hw0..hw0+63
  {
    const float* src = yln + ((size_t)b*LL + hw0)*DI;
    for (int t=tid; t<64*DI; t+=256) ls[t/DI][t%DI] = src[t];
  }
  __syncthreads();
  for (int m=0;m<DI;m++){
    float xv = ls[hwi][m];
    #pragma unroll
    for (int q=0;q<24;q++) acc[q] += Wo[(size_t)(ws*24+q)*384 + m]*xv;
  }
  __syncthreads();
  // e half: rows j = HW+hw0..
  {
    const float* src = yln + ((size_t)b*LL + HW + hw0)*DI;
    for (int t=tid; t<64*DI; t+=256) ls[t/DI][t%DI] = src[t];
  }
  __syncthreads();
  for (int m=0;m<DI;m++){
    float xv = ls[hwi][m];
    #pragma unroll
    for (int q=0;q<24;q++) acc[q] += Wo[(size_t)(ws*24+q)*384 + DI + m]*xv;
  }
  #pragma unroll
  for (int q=0;q<24;q++){
    out[((size_t)b*HW + hw0 + hwi)*DM + ws*24 + q] = acc[q];
  }
}

// ---------------- launch ----------------
extern "C" void kernel_launch(void* const* d_in, const int* in_sizes, int n_in,
                              void* d_out, int out_size, void* d_ws, size_t ws_size,
                              hipStream_t stream) {
  const float* x_rgb      = (const float*)d_in[0];
  const float* x_e        = (const float*)d_in[1];
  const float* in_proj_w  = (const float*)d_in[2];
  const float* in_proj_xw = (const float*)d_in[3];
  const float* conv_w     = (const float*)d_in[4];
  const float* conv_b     = (const float*)d_in[5];
  const float* conv_xw    = (const float*)d_in[6];
  const float* conv_xb    = (const float*)d_in[7];
  const float* xpw        = (const float*)d_in[8];
  const float* dtw        = (const float*)d_in[9];
  const float* dtb        = (const float*)d_in[10];
  const float* A_logs     = (const float*)d_in[11];
  const float* Ds         = (const float*)d_in[12];
  const float* ln1_g      = (const float*)d_in[13];
  const float* ln1_b      = (const float*)d_in[14];
  const float* ln2_g      = (const float*)d_in[15];
  const float* ln2_b      = (const float*)d_in[16];
  const float* out_proj_w = (const float*)d_in[17];
  const float* fc1_w1     = (const float*)d_in[18];
  const float* fc1_w2     = (const float*)d_in[19];
  const float* fc2_w1     = (const float*)d_in[20];
  const float* fc2_w2     = (const float*)d_in[21];

  float* ws = (float*)d_ws;
  // layout (floats). y0 aliases xr_t+xe_t (dead after k_mean); yln aliases seq (dead after k_scan).
  float* xr_t = ws;                        // 1,572,864
  float* xe_t = ws + 1572864;              // 1,572,864
  float* y0   = ws;                        // 3,145,728 (alias)
  float* seq  = ws + 3145728;              // 3,145,728
  float* yln  = seq;                       // alias
  float* pdbl = ws + 6291456;              //   458,752
  float* y1   = ws + 6750208;              // 3,145,728
  float* sr   = ws + 9895936;              //       768
  float* ex   = ws + 9896704;              //       768

  k_inproj<<<dim3(HW/64, B_, 2), 256, 0, stream>>>(x_rgb, x_e, in_proj_w, in_proj_xw, xr_t, xe_t);
  k_conv  <<<dim3(HW/256, DI, B_*2), 256, 0, stream>>>(xr_t, xe_t, conv_w, conv_b, conv_xw, conv_xb, seq);
  k_mean  <<<dim3(DI, B_, 2), 256, 0, stream>>>(xr_t, xe_t, sr);
  k_se    <<<dim3(B_, 2), DI, 0, stream>>>(sr, fc1_w1, fc1_w2, fc2_w1, fc2_w2, ex);
  k_pdbl  <<<dim3(LL/256, 14, B_*KD), 256, 0, stream>>>(seq, xpw, pdbl);
  k_scan  <<<dim3(B_*KD*DI), 256, 0, stream>>>(seq, pdbl, dtw, dtb, A_logs, Ds, y0, y1);
  k_ln    <<<dim3(LL/64, B_), 256, 0, stream>>>(y0, y1, ln1_g, ln1_b, ln2_g, ln2_b, ex, yln);
  k_out   <<<dim3(HW/64, B_), 256, 0, stream>>>(yln, out_proj_w, (float*)d_out);
}

// Round 2
// 374.532 us; speedup vs baseline: 2.2500x; 2.2500x over previous
//
#include <hip/hip_runtime.h>
#include <math.h>

#define B_  2
#define H_  64
#define W_  64
#define HW  4096
#define DM  96
#define DI  192
#define NS  4
#define RK  6
#define KD  2
#define LL  8192   // 2*HW

__device__ __forceinline__ float sigmoidf_(float x){ return 1.f/(1.f+__expf(-x)); }

// ---------------- K1: input projections -> channel-major [B,DI,HW] ----------------
__global__ __launch_bounds__(256) void k_inproj(
    const float* __restrict__ xrgb, const float* __restrict__ xe,
    const float* __restrict__ wr,   const float* __restrict__ we,
    float* __restrict__ xrt, float* __restrict__ xet)
{
  const int mod = blockIdx.z;
  const float* x  = mod ? xe  : xrgb;
  const float* Wp = mod ? we  : wr;
  float* out      = mod ? xet : xrt;
  const int b   = blockIdx.y;
  const int hw0 = blockIdx.x * 64;
  __shared__ float ls[64][97];
  const int tid = threadIdx.x;
  const float* src = x + ((size_t)b*HW + hw0)*DM;
  for (int t = tid; t < 64*DM; t += 256) ls[t/DM][t%DM] = src[t];
  __syncthreads();
  const int hw_i = tid & 63, wslot = tid >> 6;   // wslot picks 48 output channels
  float acc[48];
  #pragma unroll
  for (int q=0;q<48;q++) acc[q]=0.f;
  const float* wbase = Wp + (size_t)(wslot*48)*DM;
  for (int m=0;m<DM;m++){
    float xv = ls[hw_i][m];
    #pragma unroll
    for (int q=0;q<48;q++) acc[q] += wbase[q*DM + m] * xv;
  }
  #pragma unroll
  for (int q=0;q<48;q++){
    int dd = wslot*48 + q;
    out[((size_t)b*DI + dd)*HW + hw0 + hw_i] = acc[q];
  }
}

// ---------------- K2: depthwise 3x3 conv + SiLU -> seq[B,DI,2HW] ----------------
__global__ __launch_bounds__(256) void k_conv(
    const float* __restrict__ xrt, const float* __restrict__ xet,
    const float* __restrict__ cwr, const float* __restrict__ cbr,
    const float* __restrict__ cwe, const float* __restrict__ cbe,
    float* __restrict__ seq)
{
  const int z = blockIdx.z; const int b = z >> 1, mod = z & 1;
  const int d = blockIdx.y;
  const float* in = (mod? xet:xrt) + ((size_t)b*DI + d)*HW;
  const float* wp = (mod? cwe:cwr) + d*9;
  const float  bias = (mod? cbe:cbr)[d];
  const int hw = blockIdx.x*256 + threadIdx.x;
  const int y = hw >> 6, x = hw & 63;
  float w[9];
  #pragma unroll
  for (int i=0;i<9;i++) w[i]=wp[i];
  float acc = bias;
  #pragma unroll
  for (int dy=-1;dy<=1;dy++){
    int yy = y+dy;
    if (yy<0||yy>=H_) continue;
    #pragma unroll
    for (int dx=-1;dx<=1;dx++){
      int xx = x+dx;
      if (xx<0||xx>=W_) continue;
      acc += in[yy*W_+xx]*w[(dy+1)*3 + dx+1];
    }
  }
  float v = acc * sigmoidf_(acc);
  seq[((size_t)b*DI + d)*LL + mod*HW + hw] = v;
}

// ---------------- K3a: per-channel spatial mean of pre-conv features ----------------
__global__ __launch_bounds__(256) void k_mean(
    const float* __restrict__ xrt, const float* __restrict__ xet, float* __restrict__ sr)
{
  const int mod = blockIdx.z, b = blockIdx.y, d = blockIdx.x;
  const float* in = (mod? xet:xrt) + ((size_t)b*DI + d)*HW;
  float s = 0.f;
  for (int i=threadIdx.x; i<HW; i+=256) s += in[i];
  #pragma unroll
  for (int off=32; off; off>>=1) s += __shfl_down(s, off, 64);
  __shared__ float ps[4];
  if ((threadIdx.x & 63)==0) ps[threadIdx.x>>6] = s;
  __syncthreads();
  if (threadIdx.x==0)
    sr[((size_t)mod*B_ + b)*DI + d] = (ps[0]+ps[1]+ps[2]+ps[3]) * (1.f/HW);
}

// ---------------- K3b: squeeze-excitation MLP ----------------
__global__ void k_se(const float* __restrict__ sr,
                     const float* __restrict__ f11, const float* __restrict__ f12,
                     const float* __restrict__ f21, const float* __restrict__ f22,
                     float* __restrict__ ex)
{
  const int b = blockIdx.x, mod = blockIdx.y;
  const float* f1 = mod? f21:f11;
  const float* f2 = mod? f22:f12;
  __shared__ float s[DI];
  __shared__ float hid[12];
  const int t = threadIdx.x;
  s[t] = sr[((size_t)mod*B_ + b)*DI + t];
  __syncthreads();
  if (t < 12){
    float a=0.f;
    for (int dd=0; dd<DI; dd++) a += f1[t*DI+dd]*s[dd];
    hid[t] = a * sigmoidf_(a);
  }
  __syncthreads();
  float a=0.f;
  #pragma unroll
  for (int h=0; h<12; h++) a += f2[t*12+h]*hid[h];
  ex[((size_t)mod*B_ + b)*DI + t] = sigmoidf_(a);
}

// ---------------- K4: x_proj of seq -> packed draw[j][6], bc[j][8] ----------------
__global__ __launch_bounds__(256) void k_pdbl(
    const float* __restrict__ seq, const float* __restrict__ xpw,
    float* __restrict__ draw, float* __restrict__ bcp)
{
  const int b = blockIdx.z, k = blockIdx.y;
  const int j = blockIdx.x*256 + threadIdx.x;
  float acc[14];
  #pragma unroll
  for (int c=0;c<14;c++) acc[c]=0.f;
  const float* sp = seq + (size_t)b*DI*LL + j;
  const float* wp = xpw + (size_t)k*14*DI;
  for (int dd=0; dd<DI; dd++){
    float s = sp[(size_t)dd*LL];
    #pragma unroll
    for (int cc=0; cc<14; cc++) acc[cc] = fmaf(wp[cc*DI+dd], s, acc[cc]);
  }
  const int bk = b*KD + k;
  float2* dout = (float2*)(draw + ((size_t)bk*LL + j)*6);
  dout[0] = make_float2(acc[0],acc[1]);
  dout[1] = make_float2(acc[2],acc[3]);
  dout[2] = make_float2(acc[4],acc[5]);
  float4* bo = (float4*)(bcp + ((size_t)bk*LL + j)*8);
  bo[0] = make_float4(acc[6],acc[7],acc[8],acc[9]);
  bo[1] = make_float4(acc[10],acc[11],acc[12],acc[13]);
}

// ---------------- K5: chunked selective scan ----------------
#define CHUNK 32
#define NCH   256
__global__ __launch_bounds__(256) void k_scan(
    const float* __restrict__ seq,  const float* __restrict__ draw,
    const float* __restrict__ bcp,  const float* __restrict__ dtw,
    const float* __restrict__ dtb,  const float* __restrict__ Alogs,
    const float* __restrict__ Dsp,
    float* __restrict__ y0, float* __restrict__ y1)
{
  const int gid = blockIdx.x;
  const int d = gid % DI;
  const int k = (gid / DI) % KD;
  const int b = gid / (DI*KD);
  const int c = threadIdx.x;
  const int kd = k*DI + d;
  float A[NS];
  #pragma unroll
  for (int n=0;n<NS;n++) A[n] = -__expf(Alogs[kd*NS+n]);
  float dwv[RK];
  #pragma unroll
  for (int r=0;r<RK;r++) dwv[r] = dtw[kd*RK+r];
  const float bias = dtb[kd];
  const float Dv   = Dsp[kd];
  const float* sq = seq + ((size_t)b*DI + d)*LL;
  const int bk = b*KD + k;
  const float* drb = draw + (size_t)bk*LL*6;
  const float* bcb = bcp  + (size_t)bk*LL*8;

  __shared__ float sP[NCH][NS+1];
  __shared__ float sH[NCH][NS+1];
  __shared__ float ly[LL + (LL>>5)];   // pad-swizzled y staging (33KB)

  float de[CHUNK];
  float hP[NS], hh[NS];
  #pragma unroll
  for (int n=0;n<NS;n++){ hP[n]=1.f; hh[n]=0.f; }
  const int l0 = c*CHUNK;

  // Phase A: local chunk scan with zero init; compute & cache delta
  #pragma unroll
  for (int i=0;i<CHUNK;i++){
    int l = l0 + i;
    int j = k ? (LL-1-l) : l;
    const float2* drp = (const float2*)(drb + (size_t)j*6);
    float2 a0 = drp[0], a1 = drp[1], a2 = drp[2];
    float acc = bias + dwv[0]*a0.x + dwv[1]*a0.y + dwv[2]*a1.x
                     + dwv[3]*a1.y + dwv[4]*a2.x + dwv[5]*a2.y;
    float deltav = (acc > 20.f) ? acc : __logf(1.f + __expf(acc));
    de[i] = deltav;
    float xv = sq[j];
    float du = deltav*xv;
    const float4 Bv = *(const float4*)(bcb + (size_t)j*8);
    #pragma unroll
    for (int n=0;n<NS;n++){
      float dA = __expf(deltav*A[n]);
      float Bn = (n==0)?Bv.x:(n==1)?Bv.y:(n==2)?Bv.z:Bv.w;
      hh[n] = fmaf(dA, hh[n], du*Bn);
      hP[n] *= dA;
    }
  }
  #pragma unroll
  for (int n=0;n<NS;n++){ sP[c][n]=hP[n]; sH[c][n]=hh[n]; }
  __syncthreads();

  // Hillis-Steele inclusive scan over chunk carries
  float aC[NS], hC[NS];
  #pragma unroll
  for (int n=0;n<NS;n++){ aC[n]=hP[n]; hC[n]=hh[n]; }
  for (int s=1; s<NCH; s<<=1){
    float aO[NS], hO[NS];
    if (c >= s){
      #pragma unroll
      for (int n=0;n<NS;n++){ aO[n]=sP[c-s][n]; hO[n]=sH[c-s][n]; }
    }
    __syncthreads();
    if (c >= s){
      #pragma unroll
      for (int n=0;n<NS;n++){
        hC[n] = aC[n]*hO[n] + hC[n];
        aC[n] = aC[n]*aO[n];
        sP[c][n]=aC[n]; sH[c][n]=hC[n];
      }
    }
    __syncthreads();
  }
  float h[NS];
  #pragma unroll
  for (int n=0;n<NS;n++) h[n] = (c==0)? 0.f : sH[c-1][n];

  // Phase B: re-scan with correct init, emit y into swizzled LDS
  #pragma unroll
  for (int i=0;i<CHUNK;i++){
    int l = l0 + i;
    int j = k ? (LL-1-l) : l;
    float deltav = de[i];
    float xv = sq[j];
    float du = deltav*xv;
    float y = Dv*xv;
    const float4 Bv = *(const float4*)(bcb + (size_t)j*8);
    const float4 Cv = *(const float4*)(bcb + (size_t)j*8 + 4);
    #pragma unroll
    for (int n=0;n<NS;n++){
      float dA = __expf(deltav*A[n]);
      float Bn = (n==0)?Bv.x:(n==1)?Bv.y:(n==2)?Bv.z:Bv.w;
      float Cn = (n==0)?Cv.x:(n==1)?Cv.y:(n==2)?Cv.z:Cv.w;
      h[n] = fmaf(dA, h[n], du*Bn);
      y = fmaf(Cn, h[n], y);
    }
    ly[j + (j>>5)] = y;
  }
  __syncthreads();

  // coalesced float4 flush
  float* yo = (k ? y1 : y0) + ((size_t)b*DI + d)*LL;
  #pragma unroll
  for (int it=0; it<8; it++){
    int p = it*1024 + c*4;
    int sw = p >> 5;
    float4 v;
    v.x = ly[p   + sw];
    v.y = ly[p+1 + sw];
    v.z = ly[p+2 + sw];
    v.w = ly[p+3 + sw];
    *(float4*)(yo + p) = v;
  }
}

// ---------------- K6: merge + LayerNorm + SE scale -> yln[B,L,DI] ----------------
__global__ __launch_bounds__(256) void k_ln(
    const float* __restrict__ y0, const float* __restrict__ y1,
    const float* __restrict__ ln1g, const float* __restrict__ ln1b,
    const float* __restrict__ ln2g, const float* __restrict__ ln2b,
    const float* __restrict__ ex, float* __restrict__ yln)
{
  const int b  = blockIdx.y;
  const int j0 = blockIdx.x*64;
  __shared__ float v[DI][65];
  __shared__ float ps1[4][64], ps2[4][64];
  __shared__ float mu[64], rs[64];
  const int tid = threadIdx.x;
  const int jl = tid & 63, ds = tid >> 6;
  const float* p0 = y0 + (size_t)b*DI*LL + j0;
  const float* p1 = y1 + (size_t)b*DI*LL + j0;
  for (int it=0; it<48; it++){
    int d = ds*48 + it;
    v[d][jl] = p0[(size_t)d*LL + jl] + p1[(size_t)d*LL + jl];
  }
  __syncthreads();
  float s1=0.f, s2=0.f;
  for (int it=0; it<48; it++){
    float x = v[ds*48+it][jl];
    s1 += x; s2 += x*x;
  }
  ps1[ds][jl]=s1; ps2[ds][jl]=s2;
  __syncthreads();
  if (tid < 64){
    float t1 = ps1[0][tid]+ps1[1][tid]+ps1[2][tid]+ps1[3][tid];
    float t2 = ps2[0][tid]+ps2[1][tid]+ps2[2][tid]+ps2[3][tid];
    float m  = t1*(1.f/DI);
    float var= t2*(1.f/DI) - m*m;
    mu[tid]=m; rs[tid]=rsqrtf(var + 1e-5f);
  }
  __syncthreads();
  const int mod = (j0 >= HW) ? 1 : 0;
  const float* g  = mod? ln2g:ln1g;
  const float* bb = mod? ln2b:ln1b;
  const float* exm = ex + ((size_t)mod*B_ + b)*DI;
  for (int it=0; it<48; it++){
    int idx = it*256 + tid;
    int j = idx / DI;
    int d = idx - j*DI;
    float x = v[d][j];
    float o = (x - mu[j])*rs[j]*g[d] + bb[d];
    o *= exm[d];
    yln[((size_t)b*LL + j0 + j)*DI + d] = o;
  }
}

// ---------------- K7: output projection ----------------
__global__ __launch_bounds__(256) void k_out(
    const float* __restrict__ yln, const float* __restrict__ Wo, float* __restrict__ out)
{
  const int b   = blockIdx.y;
  const int hw0 = blockIdx.x*64;
  __shared__ float ls[64][193];
  const int tid = threadIdx.x;
  const int hwi = tid & 63, ws = tid >> 6;
  float acc[24];
  #pragma unroll
  for (int q=0;q<24;q++) acc[q]=0.f;

  {
    const float* src = yln + ((size_t)b*LL + hw0)*DI;
    for (int t=tid; t<64*DI; t+=256) ls[t/DI][t%DI] = src[t];
  }
  __syncthreads();
  for (int m=0;m<DI;m++){
    float xv = ls[hwi][m];
    #pragma unroll
    for (int q=0;q<24;q++) acc[q] += Wo[(size_t)(ws*24+q)*384 + m]*xv;
  }
  __syncthreads();
  {
    const float* src = yln + ((size_t)b*LL + HW + hw0)*DI;
    for (int t=tid; t<64*DI; t+=256) ls[t/DI][t%DI] = src[t];
  }
  __syncthreads();
  for (int m=0;m<DI;m++){
    float xv = ls[hwi][m];
    #pragma unroll
    for (int q=0;q<24;q++) acc[q] += Wo[(size_t)(ws*24+q)*384 + DI + m]*xv;
  }
  #pragma unroll
  for (int q=0;q<24;q++){
    out[((size_t)b*HW + hw0 + hwi)*DM + ws*24 + q] = acc[q];
  }
}

// ---------------- launch ----------------
extern "C" void kernel_launch(void* const* d_in, const int* in_sizes, int n_in,
                              void* d_out, int out_size, void* d_ws, size_t ws_size,
                              hipStream_t stream) {
  const float* x_rgb      = (const float*)d_in[0];
  const float* x_e        = (const float*)d_in[1];
  const float* in_proj_w  = (const float*)d_in[2];
  const float* in_proj_xw = (const float*)d_in[3];
  const float* conv_w     = (const float*)d_in[4];
  const float* conv_b     = (const float*)d_in[5];
  const float* conv_xw    = (const float*)d_in[6];
  const float* conv_xb    = (const float*)d_in[7];
  const float* xpw        = (const float*)d_in[8];
  const float* dtw        = (const float*)d_in[9];
  const float* dtb        = (const float*)d_in[10];
  const float* A_logs     = (const float*)d_in[11];
  const float* Ds         = (const float*)d_in[12];
  const float* ln1_g      = (const float*)d_in[13];
  const float* ln1_b      = (const float*)d_in[14];
  const float* ln2_g      = (const float*)d_in[15];
  const float* ln2_b      = (const float*)d_in[16];
  const float* out_proj_w = (const float*)d_in[17];
  const float* fc1_w1     = (const float*)d_in[18];
  const float* fc1_w2     = (const float*)d_in[19];
  const float* fc2_w1     = (const float*)d_in[20];
  const float* fc2_w2     = (const float*)d_in[21];

  float* ws = (float*)d_ws;
  // layout (floats). y0 aliases xr_t+xe_t (dead after k_mean); yln aliases seq (dead after k_scan).
  float* xr_t = ws;                        // 1,572,864
  float* xe_t = ws + 1572864;              // 1,572,864
  float* y0   = ws;                        // 3,145,728 (alias)
  float* seq  = ws + 3145728;              // 3,145,728
  float* yln  = seq;                       // alias
  float* draw = ws + 6291456;              //   196,608
  float* bc   = ws + 6488064;              //   262,144
  float* y1   = ws + 6750208;              // 3,145,728
  float* sr   = ws + 9895936;              //       768
  float* ex   = ws + 9896704;              //       768

  k_inproj<<<dim3(HW/64, B_, 2), 256, 0, stream>>>(x_rgb, x_e, in_proj_w, in_proj_xw, xr_t, xe_t);
  k_conv  <<<dim3(HW/256, DI, B_*2), 256, 0, stream>>>(xr_t, xe_t, conv_w, conv_b, conv_xw, conv_xb, seq);
  k_mean  <<<dim3(DI, B_, 2), 256, 0, stream>>>(xr_t, xe_t, sr);
  k_se    <<<dim3(B_, 2), DI, 0, stream>>>(sr, fc1_w1, fc1_w2, fc2_w1, fc2_w2, ex);
  k_pdbl  <<<dim3(LL/256, KD, B_), 256, 0, stream>>>(seq, xpw, draw, bc);
  k_scan  <<<dim3(B_*KD*DI), 256, 0, stream>>>(seq, draw, bc, dtw, dtb, A_logs, Ds, y0, y1);
  k_ln    <<<dim3(LL/64, B_), 256, 0, stream>>>(y0, y1, ln1_g, ln1_b, ln2_g, ln2_b, ex, yln);
  k_out   <<<dim3(HW/64, B_), 256, 0, stream>>>(yln, out_proj_w, (float*)d_out);
}

// Round 3
// 258.752 us; speedup vs baseline: 3.2568x; 1.4475x over previous
//
#include <hip/hip_runtime.h>
#include <math.h>

#define B_  2
#define H_  64
#define W_  64
#define HW  4096
#define DM  96
#define DI  192
#define NS  4
#define RK  6
#define KD  2
#define LL  8192   // 2*HW

__device__ __forceinline__ float sigmoidf_(float x){ return 1.f/(1.f+__expf(-x)); }

// ---------------- K1: input projections -> channel-major [B,DI,HW] ----------------
// LDS-staged W (full [192][96]), register-blocked 8 rows x 6 cols per thread.
__global__ __launch_bounds__(256) void k_inproj(
    const float* __restrict__ xrgb, const float* __restrict__ xe,
    const float* __restrict__ wr,   const float* __restrict__ we,
    float* __restrict__ xrt, float* __restrict__ xet)
{
  __shared__ float lsW[DI*100];
  const int mod = blockIdx.z, b = blockIdx.y;
  const int hw0 = blockIdx.x * 64;
  const float* x  = mod ? xe  : xrgb;
  const float* Wp = mod ? we  : wr;
  float* out      = mod ? xet : xrt;
  const int tid = threadIdx.x;
  for (int t = tid; t < DI*DM; t += 256){
    int di = t / DM, kk = t - di*DM;
    lsW[di*100 + kk] = Wp[t];
  }
  const int cg = tid & 31, slot = tid >> 5;   // 8 slots
  const int r0 = slot * 8;
  const float* xb = x + ((size_t)(b*HW) + hw0 + r0)*DM;
  float acc[8][6];
  #pragma unroll
  for (int i=0;i<8;i++)
    #pragma unroll
    for (int q=0;q<6;q++) acc[i][q]=0.f;
  __syncthreads();
  for (int kk4=0; kk4<DM/4; kk4++){
    float4 xv[8];
    #pragma unroll
    for (int i=0;i<8;i++) xv[i] = *(const float4*)(xb + (size_t)i*DM + kk4*4);
    #pragma unroll
    for (int q=0;q<6;q++){
      const float4 wv = *(const float4*)(&lsW[(cg+32*q)*100 + kk4*4]);
      #pragma unroll
      for (int i=0;i<8;i++){
        acc[i][q] = fmaf(xv[i].x, wv.x, acc[i][q]);
        acc[i][q] = fmaf(xv[i].y, wv.y, acc[i][q]);
        acc[i][q] = fmaf(xv[i].z, wv.z, acc[i][q]);
        acc[i][q] = fmaf(xv[i].w, wv.w, acc[i][q]);
      }
    }
  }
  #pragma unroll
  for (int q=0;q<6;q++){
    int di = cg + 32*q;
    float* ob = out + ((size_t)(b*DI + di))*HW + hw0 + r0;
    #pragma unroll
    for (int i=0;i<8;i++) ob[i] = acc[i][q];
  }
}

// ---------------- K2: depthwise 3x3 conv + SiLU -> seq[B,DI,2HW] ----------------
__global__ __launch_bounds__(256) void k_conv(
    const float* __restrict__ xrt, const float* __restrict__ xet,
    const float* __restrict__ cwr, const float* __restrict__ cbr,
    const float* __restrict__ cwe, const float* __restrict__ cbe,
    float* __restrict__ seq)
{
  const int z = blockIdx.z; const int b = z >> 1, mod = z & 1;
  const int d = blockIdx.y;
  const float* in = (mod? xet:xrt) + ((size_t)b*DI + d)*HW;
  const float* wp = (mod? cwe:cwr) + d*9;
  const float  bias = (mod? cbe:cbr)[d];
  const int hw = blockIdx.x*256 + threadIdx.x;
  const int y = hw >> 6, x = hw & 63;
  float w[9];
  #pragma unroll
  for (int i=0;i<9;i++) w[i]=wp[i];
  float acc = bias;
  #pragma unroll
  for (int dy=-1;dy<=1;dy++){
    int yy = y+dy;
    if (yy<0||yy>=H_) continue;
    #pragma unroll
    for (int dx=-1;dx<=1;dx++){
      int xx = x+dx;
      if (xx<0||xx>=W_) continue;
      acc += in[yy*W_+xx]*w[(dy+1)*3 + dx+1];
    }
  }
  float v = acc * sigmoidf_(acc);
  seq[((size_t)b*DI + d)*LL + mod*HW + hw] = v;
}

// ---------------- K3a: per-channel spatial mean of pre-conv features ----------------
__global__ __launch_bounds__(256) void k_mean(
    const float* __restrict__ xrt, const float* __restrict__ xet, float* __restrict__ sr)
{
  const int mod = blockIdx.z, b = blockIdx.y, d = blockIdx.x;
  const float* in = (mod? xet:xrt) + ((size_t)b*DI + d)*HW;
  float s = 0.f;
  for (int i=threadIdx.x; i<HW; i+=256) s += in[i];
  #pragma unroll
  for (int off=32; off; off>>=1) s += __shfl_down(s, off, 64);
  __shared__ float ps[4];
  if ((threadIdx.x & 63)==0) ps[threadIdx.x>>6] = s;
  __syncthreads();
  if (threadIdx.x==0)
    sr[((size_t)mod*B_ + b)*DI + d] = (ps[0]+ps[1]+ps[2]+ps[3]) * (1.f/HW);
}

// ---------------- K3b: squeeze-excitation MLP ----------------
__global__ void k_se(const float* __restrict__ sr,
                     const float* __restrict__ f11, const float* __restrict__ f12,
                     const float* __restrict__ f21, const float* __restrict__ f22,
                     float* __restrict__ ex)
{
  const int b = blockIdx.x, mod = blockIdx.y;
  const float* f1 = mod? f21:f11;
  const float* f2 = mod? f22:f12;
  __shared__ float s[DI];
  __shared__ float hid[12];
  const int t = threadIdx.x;
  s[t] = sr[((size_t)mod*B_ + b)*DI + t];
  __syncthreads();
  if (t < 12){
    float a=0.f;
    for (int dd=0; dd<DI; dd++) a += f1[t*DI+dd]*s[dd];
    hid[t] = a * sigmoidf_(a);
  }
  __syncthreads();
  float a=0.f;
  #pragma unroll
  for (int h=0; h<12; h++) a += f2[t*12+h]*hid[h];
  ex[((size_t)mod*B_ + b)*DI + t] = sigmoidf_(a);
}

// ---------------- K4: x_proj of seq -> packed draw[j][6], bc[j][8] ----------------
__global__ __launch_bounds__(256) void k_pdbl(
    const float* __restrict__ seq, const float* __restrict__ xpw,
    float* __restrict__ draw, float* __restrict__ bcp)
{
  const int b = blockIdx.z, k = blockIdx.y;
  const int j = blockIdx.x*256 + threadIdx.x;
  float acc[14];
  #pragma unroll
  for (int c=0;c<14;c++) acc[c]=0.f;
  const float* sp = seq + (size_t)b*DI*LL + j;
  const float* wp = xpw + (size_t)k*14*DI;
  for (int dd=0; dd<DI; dd++){
    float s = sp[(size_t)dd*LL];
    #pragma unroll
    for (int cc=0; cc<14; cc++) acc[cc] = fmaf(wp[cc*DI+dd], s, acc[cc]);
  }
  const int bk = b*KD + k;
  float2* dout = (float2*)(draw + ((size_t)bk*LL + j)*6);
  dout[0] = make_float2(acc[0],acc[1]);
  dout[1] = make_float2(acc[2],acc[3]);
  dout[2] = make_float2(acc[4],acc[5]);
  float4* bo = (float4*)(bcp + ((size_t)bk*LL + j)*8);
  bo[0] = make_float4(acc[6],acc[7],acc[8],acc[9]);
  bo[1] = make_float4(acc[10],acc[11],acc[12],acc[13]);
}

// ---------------- K5: chunked selective scan ----------------
#define CHUNK 32
#define NCH   256
__global__ __launch_bounds__(256) void k_scan(
    const float* __restrict__ seq,  const float* __restrict__ draw,
    const float* __restrict__ bcp,  const float* __restrict__ dtw,
    const float* __restrict__ dtb,  const float* __restrict__ Alogs,
    const float* __restrict__ Dsp,
    float* __restrict__ y0, float* __restrict__ y1)
{
  const int gid = blockIdx.x;
  const int d = gid % DI;
  const int k = (gid / DI) % KD;
  const int b = gid / (DI*KD);
  const int c = threadIdx.x;
  const int kd = k*DI + d;
  float A[NS];
  #pragma unroll
  for (int n=0;n<NS;n++) A[n] = -__expf(Alogs[kd*NS+n]);
  float dwv[RK];
  #pragma unroll
  for (int r=0;r<RK;r++) dwv[r] = dtw[kd*RK+r];
  const float bias = dtb[kd];
  const float Dv   = Dsp[kd];
  const float* sq = seq + ((size_t)b*DI + d)*LL;
  const int bk = b*KD + k;
  const float* drb = draw + (size_t)bk*LL*6;
  const float* bcb = bcp  + (size_t)bk*LL*8;

  __shared__ float sP[NCH][NS+1];
  __shared__ float sH[NCH][NS+1];
  __shared__ float ly[LL + (LL>>5)];   // pad-swizzled y staging (33KB)

  float de[CHUNK];
  float hP[NS], hh[NS];
  #pragma unroll
  for (int n=0;n<NS;n++){ hP[n]=1.f; hh[n]=0.f; }
  const int l0 = c*CHUNK;

  // Phase A: local chunk scan with zero init; compute & cache delta
  #pragma unroll
  for (int i=0;i<CHUNK;i++){
    int l = l0 + i;
    int j = k ? (LL-1-l) : l;
    const float2* drp = (const float2*)(drb + (size_t)j*6);
    float2 a0 = drp[0], a1 = drp[1], a2 = drp[2];
    float acc = bias + dwv[0]*a0.x + dwv[1]*a0.y + dwv[2]*a1.x
                     + dwv[3]*a1.y + dwv[4]*a2.x + dwv[5]*a2.y;
    float deltav = (acc > 20.f) ? acc : __logf(1.f + __expf(acc));
    de[i] = deltav;
    float xv = sq[j];
    float du = deltav*xv;
    const float4 Bv = *(const float4*)(bcb + (size_t)j*8);
    #pragma unroll
    for (int n=0;n<NS;n++){
      float dA = __expf(deltav*A[n]);
      float Bn = (n==0)?Bv.x:(n==1)?Bv.y:(n==2)?Bv.z:Bv.w;
      hh[n] = fmaf(dA, hh[n], du*Bn);
      hP[n] *= dA;
    }
  }
  #pragma unroll
  for (int n=0;n<NS;n++){ sP[c][n]=hP[n]; sH[c][n]=hh[n]; }
  __syncthreads();

  // Hillis-Steele inclusive scan over chunk carries
  float aC[NS], hC[NS];
  #pragma unroll
  for (int n=0;n<NS;n++){ aC[n]=hP[n]; hC[n]=hh[n]; }
  for (int s=1; s<NCH; s<<=1){
    float aO[NS], hO[NS];
    if (c >= s){
      #pragma unroll
      for (int n=0;n<NS;n++){ aO[n]=sP[c-s][n]; hO[n]=sH[c-s][n]; }
    }
    __syncthreads();
    if (c >= s){
      #pragma unroll
      for (int n=0;n<NS;n++){
        hC[n] = aC[n]*hO[n] + hC[n];
        aC[n] = aC[n]*aO[n];
        sP[c][n]=aC[n]; sH[c][n]=hC[n];
      }
    }
    __syncthreads();
  }
  float h[NS];
  #pragma unroll
  for (int n=0;n<NS;n++) h[n] = (c==0)? 0.f : sH[c-1][n];

  // Phase B: re-scan with correct init, emit y into swizzled LDS
  #pragma unroll
  for (int i=0;i<CHUNK;i++){
    int l = l0 + i;
    int j = k ? (LL-1-l) : l;
    float deltav = de[i];
    float xv = sq[j];
    float du = deltav*xv;
    float y = Dv*xv;
    const float4 Bv = *(const float4*)(bcb + (size_t)j*8);
    const float4 Cv = *(const float4*)(bcb + (size_t)j*8 + 4);
    #pragma unroll
    for (int n=0;n<NS;n++){
      float dA = __expf(deltav*A[n]);
      float Bn = (n==0)?Bv.x:(n==1)?Bv.y:(n==2)?Bv.z:Bv.w;
      float Cn = (n==0)?Cv.x:(n==1)?Cv.y:(n==2)?Cv.z:Cv.w;
      h[n] = fmaf(dA, h[n], du*Bn);
      y = fmaf(Cn, h[n], y);
    }
    ly[j + (j>>5)] = y;
  }
  __syncthreads();

  // coalesced float4 flush
  float* yo = (k ? y1 : y0) + ((size_t)b*DI + d)*LL;
  #pragma unroll
  for (int it=0; it<8; it++){
    int p = it*1024 + c*4;
    int sw = p >> 5;
    float4 v;
    v.x = ly[p   + sw];
    v.y = ly[p+1 + sw];
    v.z = ly[p+2 + sw];
    v.w = ly[p+3 + sw];
    *(float4*)(yo + p) = v;
  }
}

// ---------------- K6: merge + LayerNorm + SE scale -> yln[B,L,DI] ----------------
__global__ __launch_bounds__(256) void k_ln(
    const float* __restrict__ y0, const float* __restrict__ y1,
    const float* __restrict__ ln1g, const float* __restrict__ ln1b,
    const float* __restrict__ ln2g, const float* __restrict__ ln2b,
    const float* __restrict__ ex, float* __restrict__ yln)
{
  const int b  = blockIdx.y;
  const int j0 = blockIdx.x*64;
  __shared__ float v[DI][65];
  __shared__ float ps1[4][64], ps2[4][64];
  __shared__ float mu[64], rs[64];
  const int tid = threadIdx.x;
  const int jl = tid & 63, ds = tid >> 6;
  const float* p0 = y0 + (size_t)b*DI*LL + j0;
  const float* p1 = y1 + (size_t)b*DI*LL + j0;
  for (int it=0; it<48; it++){
    int d = ds*48 + it;
    v[d][jl] = p0[(size_t)d*LL + jl] + p1[(size_t)d*LL + jl];
  }
  __syncthreads();
  float s1=0.f, s2=0.f;
  for (int it=0; it<48; it++){
    float x = v[ds*48+it][jl];
    s1 += x; s2 += x*x;
  }
  ps1[ds][jl]=s1; ps2[ds][jl]=s2;
  __syncthreads();
  if (tid < 64){
    float t1 = ps1[0][tid]+ps1[1][tid]+ps1[2][tid]+ps1[3][tid];
    float t2 = ps2[0][tid]+ps2[1][tid]+ps2[2][tid]+ps2[3][tid];
    float m  = t1*(1.f/DI);
    float var= t2*(1.f/DI) - m*m;
    mu[tid]=m; rs[tid]=rsqrtf(var + 1e-5f);
  }
  __syncthreads();
  const int mod = (j0 >= HW) ? 1 : 0;
  const float* g  = mod? ln2g:ln1g;
  const float* bb = mod? ln2b:ln1b;
  const float* exm = ex + ((size_t)mod*B_ + b)*DI;
  for (int it=0; it<48; it++){
    int idx = it*256 + tid;
    int j = idx / DI;
    int d = idx - j*DI;
    float x = v[d][j];
    float o = (x - mu[j])*rs[j]*g[d] + bb[d];
    o *= exm[d];
    yln[((size_t)b*LL + j0 + j)*DI + d] = o;
  }
}

// ---------------- K7: output projection (LDS-W, register-blocked) ----------------
#define TMO 32
__global__ __launch_bounds__(128) void k_out(
    const float* __restrict__ yln, const float* __restrict__ Wo, float* __restrict__ out)
{
  __shared__ float lsW[DM*68];
  const int bid  = blockIdx.x;          // 0..255
  const int row0 = bid * TMO;           // global row = b*HW + hw
  const int b    = row0 >> 12;
  const int hw0  = row0 & (HW-1);
  const int tid  = threadIdx.x;
  const int cg = tid & 31, slot = tid >> 5;   // 4 slots
  const int r0 = slot * 8;                    // 8 rows per thread
  float acc[8][3];
  #pragma unroll
  for (int i=0;i<8;i++)
    #pragma unroll
    for (int q=0;q<3;q++) acc[i][q]=0.f;

  for (int c=0;c<6;c++){
    for (int t=tid; t<DM*64; t+=128){
      int dm = t>>6, kkl = t&63;
      lsW[dm*68 + kkl] = Wo[(size_t)dm*384 + c*64 + kkl];
    }
    __syncthreads();
    const float* xb = yln + ((size_t)b*LL + ((c<3)? hw0 : HW+hw0) + r0)*DI
                          + ((c<3)? c*64 : (c-3)*64);
    for (int kk4=0; kk4<16; kk4++){
      float4 xv[8];
      #pragma unroll
      for (int i=0;i<8;i++) xv[i] = *(const float4*)(xb + (size_t)i*DI + kk4*4);
      #pragma unroll
      for (int q=0;q<3;q++){
        const float4 wv = *(const float4*)(&lsW[(cg+32*q)*68 + kk4*4]);
        #pragma unroll
        for (int i=0;i<8;i++){
          acc[i][q] = fmaf(xv[i].x, wv.x, acc[i][q]);
          acc[i][q] = fmaf(xv[i].y, wv.y, acc[i][q]);
          acc[i][q] = fmaf(xv[i].z, wv.z, acc[i][q]);
          acc[i][q] = fmaf(xv[i].w, wv.w, acc[i][q]);
        }
      }
    }
    __syncthreads();
  }
  #pragma unroll
  for (int i=0;i<8;i++){
    float* ob = out + (size_t)(row0 + r0 + i)*DM;
    #pragma unroll
    for (int q=0;q<3;q++) ob[cg + 32*q] = acc[i][q];
  }
}

// ---------------- launch ----------------
extern "C" void kernel_launch(void* const* d_in, const int* in_sizes, int n_in,
                              void* d_out, int out_size, void* d_ws, size_t ws_size,
                              hipStream_t stream) {
  const float* x_rgb      = (const float*)d_in[0];
  const float* x_e        = (const float*)d_in[1];
  const float* in_proj_w  = (const float*)d_in[2];
  const float* in_proj_xw = (const float*)d_in[3];
  const float* conv_w     = (const float*)d_in[4];
  const float* conv_b     = (const float*)d_in[5];
  const float* conv_xw    = (const float*)d_in[6];
  const float* conv_xb    = (const float*)d_in[7];
  const float* xpw        = (const float*)d_in[8];
  const float* dtw        = (const float*)d_in[9];
  const float* dtb        = (const float*)d_in[10];
  const float* A_logs     = (const float*)d_in[11];
  const float* Ds         = (const float*)d_in[12];
  const float* ln1_g      = (const float*)d_in[13];
  const float* ln1_b      = (const float*)d_in[14];
  const float* ln2_g      = (const float*)d_in[15];
  const float* ln2_b      = (const float*)d_in[16];
  const float* out_proj_w = (const float*)d_in[17];
  const float* fc1_w1     = (const float*)d_in[18];
  const float* fc1_w2     = (const float*)d_in[19];
  const float* fc2_w1     = (const float*)d_in[20];
  const float* fc2_w2     = (const float*)d_in[21];

  float* ws = (float*)d_ws;
  // layout (floats). y0 aliases xr_t+xe_t (dead after k_mean); yln aliases seq (dead after k_scan).
  float* xr_t = ws;                        // 1,572,864
  float* xe_t = ws + 1572864;              // 1,572,864
  float* y0   = ws;                        // 3,145,728 (alias)
  float* seq  = ws + 3145728;              // 3,145,728
  float* yln  = seq;                       // alias
  float* draw = ws + 6291456;              //   196,608
  float* bc   = ws + 6488064;              //   262,144
  float* y1   = ws + 6750208;              // 3,145,728
  float* sr   = ws + 9895936;              //       768
  float* ex   = ws + 9896704;              //       768

  k_inproj<<<dim3(HW/64, B_, 2), 256, 0, stream>>>(x_rgb, x_e, in_proj_w, in_proj_xw, xr_t, xe_t);
  k_conv  <<<dim3(HW/256, DI, B_*2), 256, 0, stream>>>(xr_t, xe_t, conv_w, conv_b, conv_xw, conv_xb, seq);
  k_mean  <<<dim3(DI, B_, 2), 256, 0, stream>>>(xr_t, xe_t, sr);
  k_se    <<<dim3(B_, 2), DI, 0, stream>>>(sr, fc1_w1, fc1_w2, fc2_w1, fc2_w2, ex);
  k_pdbl  <<<dim3(LL/256, KD, B_), 256, 0, stream>>>(seq, xpw, draw, bc);
  k_scan  <<<dim3(B_*KD*DI), 256, 0, stream>>>(seq, draw, bc, dtw, dtb, A_logs, Ds, y0, y1);
  k_ln    <<<dim3(LL/64, B_), 256, 0, stream>>>(y0, y1, ln1_g, ln1_b, ln2_g, ln2_b, ex, yln);
  k_out   <<<dim3(8192/TMO), 128, 0, stream>>>(yln, out_proj_w, (float*)d_out);
}